// Round 3
// baseline (344.768 us; speedup 1.0000x reference)
//
#include <hip/hip_runtime.h>

#define GG 1000
#define NPG 500
#define KK 8
#define N1 128
#define N2 128
#define NEG_SLOPE 0.45f
#define NTHREADS 512
#define NWAVES 8

__global__ __launch_bounds__(NTHREADS) void cluster_attn_kernel(
    const float* __restrict__ x,
    const float* __restrict__ W1,
    const float* __restrict__ b1,
    const float* __restrict__ Wa,
    const float* __restrict__ ba,
    const int*   __restrict__ cls,
    float*       __restrict__ out)
{
    __shared__ float s_acc[KK][N1];    // 4 KB — the csum, built by ds_add_f32
    __shared__ float s_hw[KK * N2];    // 4 KB
    __shared__ int   s_cls[NPG];       // 2 KB
    __shared__ int   s_icnt[KK];
    __shared__ float s_fcnt[KK];
    __shared__ float s_ratio[KK];
    __shared__ float s_L[KK];
    __shared__ float s_e[KK];

    const int g   = blockIdx.x;
    const int tid = threadIdx.x;
    const int w   = tid >> 6;     // wave 0..7
    const int l   = tid & 63;     // lane

    const int* clsg = cls + (size_t)g * NPG;

    // ---- init: zero acc + counts, stage cls into LDS ----
    float* accf = &s_acc[0][0];
    for (int i = tid; i < KK * N1; i += NTHREADS) accf[i] = 0.f;
    if (tid < KK) s_icnt[tid] = 0;
    if (tid < NPG) s_cls[tid] = clsg[tid];
    __syncthreads();
    if (tid < NPG) atomicAdd(&s_icnt[s_cls[tid]], 1);   // overlaps with phase 1

    // ---- phase 1: fire-and-forget LDS float atomics, one node per wave-iter ----
    // Two stride-64 dword loads (256B coalesced each); ds_add addrs = c*128 + l
    // (+64) -> banks l%32, 2-way aliasing only (free).
    const float* xg = x + (size_t)g * NPG * N1;
    #pragma unroll 2
    for (int n = w; n < NPG; n += NWAVES) {
        int   c  = s_cls[n];                 // LDS broadcast (same addr all lanes)
        float f0 = xg[(size_t)n * N1 + l];
        float f1 = xg[(size_t)n * N1 + 64 + l];
        atomicAdd(&s_acc[c][l],      f0);    // ds_add_f32, no return, no chain
        atomicAdd(&s_acc[c][64 + l], f1);
    }
    __syncthreads();

    // ---- counts -> ratios ----
    if (tid == 0) {
        float d = 0.f;
        #pragma unroll
        for (int k = 0; k < KK; ++k) {
            float c = (float)s_icnt[k];
            s_fcnt[k] = c;
            d += c * c;                      // denom = sum_k c_k^2
        }
        #pragma unroll
        for (int k = 0; k < KK; ++k) s_ratio[k] = s_fcnt[k] / d;
    }
    __syncthreads();

    // ---- phase 2: h[k][j] = leaky(ratio_k*(csum_k . W1[:,j]) + b1[j]);
    //      hw[k][j] = h[k][j]*Wa[j]  (1024 dots over 512 threads) ----
    #pragma unroll
    for (int r = 0; r < 2; ++r) {
        int idx = tid + r * NTHREADS;        // 0..1023
        int k = idx >> 7;
        int j = idx & 127;
        float s = 0.f;
        #pragma unroll 4
        for (int f = 0; f < N1; ++f)
            s = fmaf(accf[k * N1 + f], W1[f * N2 + j], s);  // LDS broadcast x coalesced W1
        float val = fmaf(s, s_ratio[k], b1[j]);
        float h = val > 0.f ? val : NEG_SLOPE * val;
        s_hw[idx] = h * Wa[j];
    }
    __syncthreads();

    // ---- per-k reduce: wave w owns cluster k=w ----
    {
        float v = s_hw[w * 128 + l] + s_hw[w * 128 + 64 + l];
        #pragma unroll
        for (int off = 32; off > 0; off >>= 1) v += __shfl_down(v, off);
        if (l == 0) s_L[w] = v + ba[0];
    }
    __syncthreads();

    // ---- phase 3: count-weighted softmax over 8 clusters (skip empty) ----
    if (tid == 0) {
        float m = -1e30f;
        #pragma unroll
        for (int k = 0; k < KK; ++k)
            if (s_fcnt[k] > 0.f) m = fmaxf(m, s_L[k]);
        float ssum = 0.f;
        float ek[KK];
        #pragma unroll
        for (int k = 0; k < KK; ++k) {
            ek[k] = (s_fcnt[k] > 0.f) ? expf(s_L[k] - m) : 0.f;
            ssum += s_fcnt[k] * ek[k];
        }
        #pragma unroll
        for (int k = 0; k < KK; ++k) s_e[k] = ek[k] / ssum;
    }
    __syncthreads();

    // ---- phase 4: per-node output = table lookup from staged cls ----
    float* outg = out + (size_t)g * NPG;
    for (int n = tid; n < NPG; n += NTHREADS) outg[n] = s_e[s_cls[n]];
}

extern "C" void kernel_launch(void* const* d_in, const int* in_sizes, int n_in,
                              void* d_out, int out_size, void* d_ws, size_t ws_size,
                              hipStream_t stream) {
    const float* x   = (const float*)d_in[0];
    const float* W1  = (const float*)d_in[1];
    const float* b1  = (const float*)d_in[2];
    const float* Wa  = (const float*)d_in[3];
    const float* ba  = (const float*)d_in[4];
    const int*   cls = (const int*)d_in[5];
    // d_in[6] = batch: sorted repeat(arange(G), NPG) by construction -> implicit

    float* out = (float*)d_out;
    cluster_attn_kernel<<<GG, NTHREADS, 0, stream>>>(x, W1, b1, Wa, ba, cls, out);
}

// Round 4
// 79.218 us; speedup vs baseline: 4.3521x; 4.3521x over previous
//
#include <hip/hip_runtime.h>

#define GG 1000
#define NPG 500
#define KK 8
#define N1 128
#define N2 128
#define NEG_SLOPE 0.45f
#define NTHREADS 512
#define NWAVES 8

__global__ __launch_bounds__(NTHREADS) void cluster_attn_kernel(
    const float* __restrict__ x,
    const float* __restrict__ W1,
    const float* __restrict__ b1,
    const float* __restrict__ Wa,
    const float* __restrict__ ba,
    const int*   __restrict__ cls,
    float*       __restrict__ out)
{
    __shared__ float s_acc[NWAVES][KK][N1];   // 32 KB wave partials; [0] -> csum
    __shared__ float s_hw[KK * N2];           // 4 KB
    __shared__ int   s_cls[NPG];              // 2 KB
    __shared__ float s_cnt[NWAVES][KK];
    __shared__ float s_fcnt[KK];
    __shared__ float s_ratio[KK];
    __shared__ float s_L[KK];
    __shared__ float s_e[KK];

    const int g   = blockIdx.x;
    const int tid = threadIdx.x;
    const int w   = tid >> 6;     // wave 0..7
    const int l   = tid & 63;     // lane

    const int* clsg = cls + (size_t)g * NPG;
    if (tid < NPG) s_cls[tid] = clsg[tid];
    __syncthreads();

    // ---- phase 1: one wave per node; cluster id is wave-uniform -> scalar
    //      switch into REGISTER accumulators (no LDS RMW, no masked FMAs) ----
    float ax[KK], ay[KK];
    int   cnt[KK];
    #pragma unroll
    for (int k = 0; k < KK; ++k) { ax[k] = 0.f; ay[k] = 0.f; cnt[k] = 0; }

    const float2* x2 = (const float2*)(x + (size_t)g * NPG * N1);

#define ACCUM(c, v)                                                     \
    switch (c) {                                                        \
    case 0: ax[0]+=v.x; ay[0]+=v.y; cnt[0]++; break;                    \
    case 1: ax[1]+=v.x; ay[1]+=v.y; cnt[1]++; break;                    \
    case 2: ax[2]+=v.x; ay[2]+=v.y; cnt[2]++; break;                    \
    case 3: ax[3]+=v.x; ay[3]+=v.y; cnt[3]++; break;                    \
    case 4: ax[4]+=v.x; ay[4]+=v.y; cnt[4]++; break;                    \
    case 5: ax[5]+=v.x; ay[5]+=v.y; cnt[5]++; break;                    \
    case 6: ax[6]+=v.x; ay[6]+=v.y; cnt[6]++; break;                    \
    default: ax[7]+=v.x; ay[7]+=v.y; cnt[7]++; break;                   \
    }

    int n = w;
    for (; n + 3 * NWAVES < NPG; n += 4 * NWAVES) {
        // 4 loads issued back-to-back: 4x512B in flight per wave
        int c0 = __builtin_amdgcn_readfirstlane(s_cls[n]);
        int c1 = __builtin_amdgcn_readfirstlane(s_cls[n + NWAVES]);
        int c2 = __builtin_amdgcn_readfirstlane(s_cls[n + 2 * NWAVES]);
        int c3 = __builtin_amdgcn_readfirstlane(s_cls[n + 3 * NWAVES]);
        float2 v0 = x2[(size_t)n * 64 + l];
        float2 v1 = x2[(size_t)(n + NWAVES) * 64 + l];
        float2 v2 = x2[(size_t)(n + 2 * NWAVES) * 64 + l];
        float2 v3 = x2[(size_t)(n + 3 * NWAVES) * 64 + l];
        ACCUM(c0, v0); ACCUM(c1, v1); ACCUM(c2, v2); ACCUM(c3, v3);
    }
    for (; n < NPG; n += NWAVES) {
        int c = __builtin_amdgcn_readfirstlane(s_cls[n]);
        float2 v = x2[(size_t)n * 64 + l];
        ACCUM(c, v);
    }
#undef ACCUM

    // ---- spill per-wave partials (lane l owns features 2l,2l+1) ----
    #pragma unroll
    for (int k = 0; k < KK; ++k) {
        float2* dst = (float2*)&s_acc[w][k][0];
        dst[l] = make_float2(ax[k], ay[k]);
    }
    if (l == 0) {
        #pragma unroll
        for (int k = 0; k < KK; ++k) s_cnt[w][k] = (float)cnt[k];
    }
    __syncthreads();

    // ---- reduce 8 wave partials into s_acc[0]; counts -> ratios ----
    float* accf = &s_acc[0][0][0];
    for (int e = tid; e < KK * N1; e += NTHREADS) {
        float s = 0.f;
        #pragma unroll
        for (int ww = 0; ww < NWAVES; ++ww) s += s_acc[ww][0][e];
        accf[e] = s;   // each thread overwrites only its own element: safe
    }
    if (tid == 0) {
        float d = 0.f;
        #pragma unroll
        for (int k = 0; k < KK; ++k) {
            float c = 0.f;
            #pragma unroll
            for (int ww = 0; ww < NWAVES; ++ww) c += s_cnt[ww][k];
            s_fcnt[k] = c;
            d += c * c;                      // denom = sum_k c_k^2
        }
        #pragma unroll
        for (int k = 0; k < KK; ++k) s_ratio[k] = s_fcnt[k] / d;
    }
    __syncthreads();

    // ---- phase 2: h[k][j] = leaky(ratio_k*(csum_k . W1[:,j]) + b1[j]);
    //      hw[k][j] = h[k][j]*Wa[j]  (1024 dots over 512 threads) ----
    #pragma unroll
    for (int r = 0; r < 2; ++r) {
        int idx = tid + r * NTHREADS;        // 0..1023
        int k = idx >> 7;
        int j = idx & 127;
        float s = 0.f;
        #pragma unroll 4
        for (int f = 0; f < N1; ++f)
            s = fmaf(accf[k * N1 + f], W1[f * N2 + j], s);  // LDS broadcast x coalesced W1
        float val = fmaf(s, s_ratio[k], b1[j]);
        float h = val > 0.f ? val : NEG_SLOPE * val;
        s_hw[idx] = h * Wa[j];
    }
    __syncthreads();

    // ---- per-k reduce: wave w owns cluster k=w ----
    {
        float v = s_hw[w * 128 + l] + s_hw[w * 128 + 64 + l];
        #pragma unroll
        for (int off = 32; off > 0; off >>= 1) v += __shfl_down(v, off);
        if (l == 0) s_L[w] = v + ba[0];
    }
    __syncthreads();

    // ---- phase 3: count-weighted softmax over 8 clusters (skip empty) ----
    if (tid == 0) {
        float m = -1e30f;
        #pragma unroll
        for (int k = 0; k < KK; ++k)
            if (s_fcnt[k] > 0.f) m = fmaxf(m, s_L[k]);
        float ssum = 0.f;
        float ek[KK];
        #pragma unroll
        for (int k = 0; k < KK; ++k) {
            ek[k] = (s_fcnt[k] > 0.f) ? expf(s_L[k] - m) : 0.f;
            ssum += s_fcnt[k] * ek[k];
        }
        #pragma unroll
        for (int k = 0; k < KK; ++k) s_e[k] = ek[k] / ssum;
    }
    __syncthreads();

    // ---- phase 4: per-node output = table lookup from staged cls ----
    float* outg = out + (size_t)g * NPG;
    for (int n2 = tid; n2 < NPG; n2 += NTHREADS) outg[n2] = s_e[s_cls[n2]];
}

extern "C" void kernel_launch(void* const* d_in, const int* in_sizes, int n_in,
                              void* d_out, int out_size, void* d_ws, size_t ws_size,
                              hipStream_t stream) {
    const float* x   = (const float*)d_in[0];
    const float* W1  = (const float*)d_in[1];
    const float* b1  = (const float*)d_in[2];
    const float* Wa  = (const float*)d_in[3];
    const float* ba  = (const float*)d_in[4];
    const int*   cls = (const int*)d_in[5];
    // d_in[6] = batch: sorted repeat(arange(G), NPG) by construction -> implicit

    float* out = (float*)d_out;
    cluster_attn_kernel<<<GG, NTHREADS, 0, stream>>>(x, W1, b1, Wa, ba, cls, out);
}

// Round 5
// 59.642 us; speedup vs baseline: 5.7807x; 1.3282x over previous
//
#include <hip/hip_runtime.h>

#define GG 1000
#define NPG 500
#define KK 8
#define N1 128
#define N2 128
#define NEG_SLOPE 0.45f
#define NTHREADS 512
#define NWAVES 8
#define CHUNK ((NPG + NWAVES - 1) / NWAVES)   // 63

__global__ __launch_bounds__(NTHREADS) void cluster_attn_kernel(
    const float* __restrict__ x,
    const float* __restrict__ W1,
    const float* __restrict__ b1,
    const float* __restrict__ Wa,
    const float* __restrict__ ba,
    const int*   __restrict__ cls,
    float*       __restrict__ out)
{
    __shared__ float s_acc[KK][N1];        // 4 KB shared csum (rare atomic flushes)
    __shared__ float s_hw[KK * N2];        // 4 KB
    __shared__ int   s_cls[NPG];           // 2 KB
    __shared__ int   s_order[NPG];         // 2 KB: node | (cluster<<12), cluster-sorted
    __shared__ int   s_wcnt[NWAVES][KK];   // per-wave cluster histograms
    __shared__ int   s_start[KK];
    __shared__ float s_fcnt[KK];
    __shared__ float s_ratio[KK];
    __shared__ float s_L[KK];
    __shared__ float s_e[KK];

    const int g   = blockIdx.x;
    const int tid = threadIdx.x;
    const int w   = tid >> 6;     // wave 0..7
    const int l   = tid & 63;     // lane

    const int* clsg = cls + (size_t)g * NPG;
    float* accf = &s_acc[0][0];
    for (int i = tid; i < KK * N1; i += NTHREADS) accf[i] = 0.f;

    int myc = -1;
    if (tid < NPG) { myc = clsg[tid]; s_cls[tid] = myc; }

    // ---- deterministic bucket ranks via wave ballots (no atomics) ----
    unsigned long long mymask = 0;
    #pragma unroll
    for (int k = 0; k < KK; ++k) {
        unsigned long long m = __ballot(myc == k);
        if (l == 0) s_wcnt[w][k] = (int)__popcll(m);
        if (myc == k) mymask = m;
    }
    __syncthreads();

    if (tid == 0) {                         // totals, bucket starts, ratios
        int run = 0; float d = 0.f;
        #pragma unroll
        for (int k = 0; k < KK; ++k) {
            int t = 0;
            #pragma unroll
            for (int ww = 0; ww < NWAVES; ++ww) t += s_wcnt[ww][k];
            s_start[k] = run; run += t;
            float c = (float)t; s_fcnt[k] = c; d += c * c;
        }
        #pragma unroll
        for (int k = 0; k < KK; ++k) s_ratio[k] = s_fcnt[k] / d;
    }
    __syncthreads();

    if (tid < NPG) {                        // deterministic scatter into sorted order
        int before = 0;
        for (int ww = 0; ww < w; ++ww) before += s_wcnt[ww][myc];
        before += (int)__popcll(mymask & ((1ULL << l) - 1ULL));
        s_order[s_start[myc] + before] = tid | (myc << 12);
    }
    __syncthreads();

    // ---- phase 1: wave walks a contiguous cluster-sorted chunk.
    //      Inner loop = load + 2 v_add. Flush only on (rare) run boundary. ----
    const float2* x2 = (const float2*)(x + (size_t)g * NPG * N1);
    {
        int begin = w * CHUNK;
        int end   = begin + CHUNK; if (end > NPG) end = NPG;
        if (begin < end) {
            int cur = __builtin_amdgcn_readfirstlane(s_order[begin]) >> 12;
            float a0 = 0.f, a1 = 0.f;
            int e = begin;

#define STEP(P, V)                                                      \
            {                                                           \
                int c_ = (P) >> 12;                                     \
                if (c_ != cur) {            /* wave-uniform, rare */    \
                    atomicAdd(&s_acc[cur][2 * l],     a0);              \
                    atomicAdd(&s_acc[cur][2 * l + 1], a1);              \
                    a0 = 0.f; a1 = 0.f; cur = c_;                       \
                }                                                       \
                a0 += (V).x; a1 += (V).y;                               \
            }

            for (; e + 4 <= end; e += 4) {
                int p0 = __builtin_amdgcn_readfirstlane(s_order[e]);
                int p1 = __builtin_amdgcn_readfirstlane(s_order[e + 1]);
                int p2 = __builtin_amdgcn_readfirstlane(s_order[e + 2]);
                int p3 = __builtin_amdgcn_readfirstlane(s_order[e + 3]);
                float2 v0 = x2[(size_t)(p0 & 0xFFF) * 64 + l];   // 4x512B in flight
                float2 v1 = x2[(size_t)(p1 & 0xFFF) * 64 + l];
                float2 v2 = x2[(size_t)(p2 & 0xFFF) * 64 + l];
                float2 v3 = x2[(size_t)(p3 & 0xFFF) * 64 + l];
                STEP(p0, v0) STEP(p1, v1) STEP(p2, v2) STEP(p3, v3)
            }
            for (; e < end; ++e) {
                int p = __builtin_amdgcn_readfirstlane(s_order[e]);
                float2 v = x2[(size_t)(p & 0xFFF) * 64 + l];
                STEP(p, v)
            }
#undef STEP
            atomicAdd(&s_acc[cur][2 * l],     a0);   // final run flush
            atomicAdd(&s_acc[cur][2 * l + 1], a1);
        }
    }
    __syncthreads();

    // ---- phase 2: h[k][j] = leaky(ratio_k*(csum_k . W1[:,j]) + b1[j]);
    //      hw[k][j] = h[k][j]*Wa[j]  (1024 dots over 512 threads) ----
    #pragma unroll
    for (int r = 0; r < 2; ++r) {
        int idx = tid + r * NTHREADS;        // 0..1023
        int k = idx >> 7;
        int j = idx & 127;
        float s = 0.f;
        #pragma unroll 4
        for (int f = 0; f < N1; ++f)
            s = fmaf(accf[k * N1 + f], W1[f * N2 + j], s);
        float val = fmaf(s, s_ratio[k], b1[j]);
        float h = val > 0.f ? val : NEG_SLOPE * val;
        s_hw[idx] = h * Wa[j];
    }
    __syncthreads();

    // ---- per-k reduce: wave w owns cluster k=w ----
    {
        float v = s_hw[w * 128 + l] + s_hw[w * 128 + 64 + l];
        #pragma unroll
        for (int off = 32; off > 0; off >>= 1) v += __shfl_down(v, off);
        if (l == 0) s_L[w] = v + ba[0];
    }
    __syncthreads();

    // ---- phase 3: count-weighted softmax over 8 clusters (skip empty) ----
    if (tid == 0) {
        float m = -1e30f;
        #pragma unroll
        for (int k = 0; k < KK; ++k)
            if (s_fcnt[k] > 0.f) m = fmaxf(m, s_L[k]);
        float ssum = 0.f;
        float ek[KK];
        #pragma unroll
        for (int k = 0; k < KK; ++k) {
            ek[k] = (s_fcnt[k] > 0.f) ? expf(s_L[k] - m) : 0.f;
            ssum += s_fcnt[k] * ek[k];
        }
        #pragma unroll
        for (int k = 0; k < KK; ++k) s_e[k] = ek[k] / ssum;
    }
    __syncthreads();

    // ---- phase 4: per-node output = table lookup from staged cls ----
    float* outg = out + (size_t)g * NPG;
    for (int n = tid; n < NPG; n += NTHREADS) outg[n] = s_e[s_cls[n]];
}

extern "C" void kernel_launch(void* const* d_in, const int* in_sizes, int n_in,
                              void* d_out, int out_size, void* d_ws, size_t ws_size,
                              hipStream_t stream) {
    const float* x   = (const float*)d_in[0];
    const float* W1  = (const float*)d_in[1];
    const float* b1  = (const float*)d_in[2];
    const float* Wa  = (const float*)d_in[3];
    const float* ba  = (const float*)d_in[4];
    const int*   cls = (const int*)d_in[5];
    // d_in[6] = batch: sorted repeat(arange(G), NPG) by construction -> implicit

    float* out = (float*)d_out;
    cluster_attn_kernel<<<GG, NTHREADS, 0, stream>>>(x, W1, b1, Wa, ba, cls, out);
}